// Round 21
// baseline (910.005 us; speedup 1.0000x reference)
//
#include <hip/hip_runtime.h>
#include <hip/hip_bf16.h>

#define N_NODES 10000
#define N_EDGES 320000
#define HDIM 128
#define NODE_IN 64
#define EDGE_IN 16
#define NLAYERS 4
#define EPSV 1e-8f
#define SACT 136       // LDS activation row stride (elems)
#define INV4096 2.44140625e-4f

typedef unsigned short ushort_t;
typedef __attribute__((ext_vector_type(8))) short s8;        // 8 fp16 bit-pattern (4 VGPRs)
typedef __attribute__((ext_vector_type(8))) _Float16 h8;
typedef __attribute__((ext_vector_type(4))) float f4;

// silu via v_rcp_f32 (1 ulp) instead of IEEE divide (~10 instr)
__device__ __forceinline__ float silu_f(float z) {
    return z * __builtin_amdgcn_rcpf(1.0f + __expf(-z));
}
// tanh(x) = 1 - 2*rcp(exp(2x)+1); exact limits at +-inf
__device__ __forceinline__ float tanh_fast(float x) {
    float e = __expf(2.0f * x);
    return 1.0f - 2.0f * __builtin_amdgcn_rcpf(e + 1.0f);
}

__device__ __forceinline__ f4 mfma16(s8 a, s8 b, f4 c) {
    return __builtin_amdgcn_mfma_f32_16x16x32_f16(
        __builtin_bit_cast(h8, a), __builtin_bit_cast(h8, b), c, 0, 0, 0);
}

// fp32 -> fp16 hi + (residual*4096) lo   (rep error ~2^-23 relative)
__device__ __forceinline__ void split_f16(float x, ushort_t& hi, ushort_t& lo) {
    _Float16 h = (_Float16)x;
    float hf = (float)h;
    _Float16 l = (_Float16)((x - hf) * 4096.0f);
    hi = __builtin_bit_cast(ushort_t, h);
    lo = __builtin_bit_cast(ushort_t, l);
}
__device__ __forceinline__ ushort_t f2h(float x) {
    _Float16 h = (_Float16)x;
    return __builtin_bit_cast(ushort_t, h);
}

// ============ CSR build ============
__global__ void deg_kernel(const int* __restrict__ ei, int* __restrict__ deg) {
    int e = blockIdx.x * 256 + threadIdx.x;
    if (e < N_EDGES) atomicAdd(&deg[ei[e]], 1);
}

__global__ void scan_kernel(const int* __restrict__ deg, int* __restrict__ row_start,
                            int* __restrict__ cursor) {
    __shared__ int s_part[256];
    const int CH = 40;   // 256*40 = 10240 >= N_NODES
    int t = threadIdx.x;
    int base = t * CH;
    int sum = 0;
    for (int i = 0; i < CH; ++i) { int n = base + i; if (n < N_NODES) sum += deg[n]; }
    s_part[t] = sum;
    __syncthreads();
    for (int d = 1; d < 256; d <<= 1) {
        int v = (t >= d) ? s_part[t - d] : 0;
        __syncthreads();
        s_part[t] += v;
        __syncthreads();
    }
    int off = s_part[t] - sum;
    for (int i = 0; i < CH; ++i) {
        int n = base + i;
        if (n < N_NODES) { row_start[n] = off; cursor[n] = off; off += deg[n]; }
    }
    if (t == 255) row_start[N_NODES] = s_part[255];
}

__global__ void scatter_kernel(const int* __restrict__ ei, int* __restrict__ cursor,
                               int* __restrict__ csr_eid) {
    int e = blockIdx.x * 256 + threadIdx.x;
    if (e < N_EDGES) {
        int r = ei[e];
        int pos = atomicAdd(&cursor[r], 1);
        csr_eid[pos] = e;
    }
}

// ============ one-time slot-order prepack: rows/cols + ea split fp16 ============
__global__ void prep_edges(const int* __restrict__ ei, const int* __restrict__ csr_eid,
                           const float* __restrict__ ea,
                           int* __restrict__ rows_s, int* __restrict__ cols_s,
                           ushort_t* __restrict__ eah, ushort_t* __restrict__ eal) {
    int slot = blockIdx.x * 256 + threadIdx.x;
    if (slot >= N_EDGES) return;
    int eid = csr_eid[slot];
    rows_s[slot] = ei[eid];
    cols_s[slot] = ei[N_EDGES + eid];
    const float* src = ea + (size_t)eid * EDGE_IN;
#pragma unroll
    for (int i = 0; i < EDGE_IN; ++i) {
        ushort_t hh, ll;
        split_f16(src[i], hh, ll);
        eah[(size_t)slot * EDGE_IN + i] = hh;
        eal[(size_t)slot * EDGE_IN + i] = ll;
    }
}

// ============ prep 1: repack W1a,W1b,W2,C1 into MFMA B-frag order, fp16 hi only ============
__global__ void repack_weights(const float* __restrict__ ew1, const float* __restrict__ ew2,
                               const float* __restrict__ cw1,
                               ushort_t* __restrict__ wf_hi) {
    int gid = blockIdx.x * 256 + threadIdx.x;
    const int total = NLAYERS * 4 * 16384;
    if (gid >= total) return;
    int l   = gid / (4 * 16384);
    int rem = gid % (4 * 16384);
    int m4  = rem / 16384;
    int idx = rem & 16383;
    int b    = idx >> 9;
    int lane = (idx >> 3) & 63;
    int j    = idx & 7;
    int nt = b >> 2, kt = b & 3;
    int k = kt * 32 + ((lane >> 4) << 3) + j;
    int n = (nt << 4) + (lane & 15);
    float v;
    if (m4 == 0)      v = ew1[(size_t)l * 385 * 128 + (size_t)k * 128 + n];
    else if (m4 == 1) v = ew1[(size_t)l * 385 * 128 + (size_t)(128 + k) * 128 + n];
    else if (m4 == 2) v = ew2[(size_t)l * 16384 + k * 128 + n];
    else              v = cw1[(size_t)l * 16384 + k * 128 + n];
    wf_hi[gid] = f2h(v);
}

// ============ prep 2: G = eew @ W1c (K rows 0-15) + d2 weight row at k=16; frag-packed, split ============
__global__ void prep_g(const float* __restrict__ eew, const float* __restrict__ eeb,
                       const float* __restrict__ ew1, const float* __restrict__ eb1,
                       ushort_t* __restrict__ g_hi, ushort_t* __restrict__ g_lo,
                       float* __restrict__ bias1c) {
    int gid = blockIdx.x * 256 + threadIdx.x;
    const int T1 = NLAYERS * 4096;
    if (gid < T1) {
        int l = gid >> 12;
        int idx = gid & 4095;
        int nt = idx >> 9;
        int lane = (idx >> 3) & 63;
        int j = idx & 7;
        int q = lane >> 4;
        int n = (nt << 4) + (lane & 15);
        int k = q * 8 + j;
        float v = 0.f;
        if (k < EDGE_IN) {
            const float* w1c = ew1 + (size_t)l * 385 * 128 + (size_t)257 * 128;
            float acc = 0.f;
            for (int c = 0; c < HDIM; ++c) acc += eew[k * 128 + c] * w1c[(size_t)c * 128 + n];
            v = acc;
        } else if (k == EDGE_IN) {
            v = ew1[(size_t)l * 385 * 128 + (size_t)256 * 128 + n];   // d2 weight row
        }
        split_f16(v, g_hi[gid], g_lo[gid]);
    } else if (gid < T1 + NLAYERS * 128) {
        int r = gid - T1;
        int l = r >> 7;
        int n = r & 127;
        const float* w1c = ew1 + (size_t)l * 385 * 128 + (size_t)257 * 128;
        float acc = eb1[l * 128 + n];
        for (int c = 0; c < HDIM; ++c) acc += eeb[c] * w1c[(size_t)c * 128 + n];
        bias1c[r] = acc;
    }
}

// ============ t_emb ============
__global__ void temb_kernel(const float* t, const float* tw1, const float* tb1,
                            const float* tw2, const float* tb2, float* t_emb) {
    __shared__ float s_a[HDIM];
    int j = threadIdx.x;
    s_a[j] = silu_f(t[0] * tw1[j] + tb1[j]);
    __syncthreads();
    float acc = tb2[j];
    for (int k = 0; k < HDIM; ++k) acc += s_a[k] * tw2[k * HDIM + j];
    t_emb[j] = acc;
}

// ============ h_feat init: 8 nodes/block, weights amortized ============
__global__ __launch_bounds__(128) void hfeat_kernel(
    const float* __restrict__ h, const float* __restrict__ new_,
    const float* __restrict__ neb, const float* __restrict__ t_emb,
    float* __restrict__ h_feat, ushort_t* __restrict__ hbf_hi) {
    __shared__ float s_h[8][NODE_IN];
    int nb = blockIdx.x * 8, j = threadIdx.x;
#pragma unroll
    for (int it = 0; it < 4; ++it) {
        int idx = it * 128 + j;
        int e = idx >> 6, i = idx & 63;
        s_h[e][i] = h[(size_t)(nb + e) * NODE_IN + i];
    }
    __syncthreads();
    float base = neb[j] + t_emb[j];
    float acc[8];
#pragma unroll
    for (int e = 0; e < 8; ++e) acc[e] = base;
    for (int i = 0; i < NODE_IN; i += 2) {
        float w0 = new_[i * HDIM + j];
        float w1 = new_[(i + 1) * HDIM + j];
#pragma unroll
        for (int e = 0; e < 8; ++e)
            acc[e] += s_h[e][i] * w0 + s_h[e][i + 1] * w1;
    }
#pragma unroll
    for (int e = 0; e < 8; ++e) {
        h_feat[(size_t)(nb + e) * HDIM + j] = acc[e];
        hbf_hi[(size_t)(nb + e) * HDIM + j] = f2h(acc[e]);
    }
}

__global__ void xinit_kernel(const float* x, float* x_cur) {
    int idx = blockIdx.x * blockDim.x + threadIdx.x;
    if (idx < N_NODES * 3) x_cur[idx] = x[idx];
}

// ============ MFMA edge kernel: 1 block = 1 wave = 32 CSR slots (2 M-tiles) ============
// GEMM1: h-terms fp16-hi, ea/d2 keep lo correction (via G). GEMM2/GEMM3 hi-only.
// B-frags double-buffered across nt.
// (64,3): retry now that footprint shrank ~64 regs (aRl + lo dbuf removed); cap ~170 >= ~128 needed.
__global__ __launch_bounds__(64, 3) void edge_mfma_kernel(
    const int* __restrict__ rows_s, const int* __restrict__ cols_s,
    const ushort_t* __restrict__ eah, const ushort_t* __restrict__ eal,
    const float* __restrict__ x_cur,
    const ushort_t* __restrict__ hbf_hi,
    const ushort_t* __restrict__ wf_hi,
    const ushort_t* __restrict__ g_hi, const ushort_t* __restrict__ g_lo,
    const float* __restrict__ bias1c,
    const float* __restrict__ eb2, const float* __restrict__ cb1, const float* __restrict__ cw2,
    int layer, float* __restrict__ agg_h, float* __restrict__ agg_x)
{
    __shared__ __align__(16) ushort_t s_acth[32 * SACT];
    __shared__ float s_d2[32], s_dist[32], s_diff[32][3];
    __shared__ int s_row[32], s_col[32];
    __shared__ int s_drows[32];
    __shared__ int s_dcnt[1];

    const int lane = threadIdx.x;
    const int lo = lane & 15, q = lane >> 4;
    const int e0 = blockIdx.x * 32;

    const ushort_t* wAh  = wf_hi + (size_t)layer * 4 * 16384;
    const ushort_t* wBh  = wAh + 16384;
    const ushort_t* wW2h = wAh + 32768;
    const ushort_t* wC1h = wAh + 49152;
    const ushort_t* wgh  = g_hi + (size_t)layer * 4096;
    const ushort_t* wgl  = g_lo + (size_t)layer * 4096;
    const float* b1v = bias1c + layer * 128;
    const float* b2v = eb2 + layer * 128;
    const float* cbv = cb1 + layer * 128;
    const float* c2v = cw2 + layer * 128;

    // ---- phase 0: geometry for 32 slots (coalesced slot-order reads) ----
    if (lane < 32) {
        int slot = e0 + lane;
        int r = rows_s[slot], c = cols_s[slot];
        s_row[lane] = r; s_col[lane] = c;
        float dx = x_cur[r * 3 + 0] - x_cur[c * 3 + 0];
        float dy = x_cur[r * 3 + 1] - x_cur[c * 3 + 1];
        float dz = x_cur[r * 3 + 2] - x_cur[c * 3 + 2];
        float d2 = dx * dx + dy * dy + dz * dz;
        s_d2[lane] = d2;
        s_dist[lane] = sqrtf(d2 + EPSV);
        s_diff[lane][0] = dx; s_diff[lane][1] = dy; s_diff[lane][2] = dz;
    }
    __syncthreads();   // B1 (single-wave: cheap)

    // distinct-row list via ballot (CSR slots row-sorted)
    {
        bool head = false;
        if (lane < 32) {
            int r = s_row[lane];
            int prev = (lane == 0) ? -1 : s_row[lane - 1];
            head = (r != prev);
        }
        unsigned long long b = __ballot(head);
        if (head) {
            int idx = __popcll(b & ((1ull << lane) - 1ull));
            s_drows[idx] = s_row[lane];
        }
        if (lane == 0) s_dcnt[0] = __popcll(b);
    }

    // ---- A fragments for both tiles (hi only) ----
    int erT[2], ecT[2];
#pragma unroll
    for (int t = 0; t < 2; ++t) { erT[t] = s_row[t * 16 + lo]; ecT[t] = s_col[t * 16 + lo]; }

    s8 aRh[2][4], aCh[2][4];
#pragma unroll
    for (int t = 0; t < 2; ++t)
#pragma unroll
        for (int kt = 0; kt < 4; ++kt) {
            aRh[t][kt] = *(const s8*)(hbf_hi + (size_t)erT[t] * 128 + kt * 32 + q * 8);
            aCh[t][kt] = *(const s8*)(hbf_hi + (size_t)ecT[t] * 128 + kt * 32 + q * 8);
        }
    // ea (k=0..15, prepacked fp16 split, coalesced) + d2 (k=16, lanes q==2 slot j=0)
    s8 aEAh[2], aEAl[2];
#pragma unroll
    for (int t = 0; t < 2; ++t) {
        aEAh[t] = (s8){0,0,0,0,0,0,0,0};
        aEAl[t] = (s8){0,0,0,0,0,0,0,0};
        if (q < 2) {
            size_t off = (size_t)(e0 + t * 16 + lo) * EDGE_IN + q * 8;
            aEAh[t] = *(const s8*)(eah + off);
            aEAl[t] = *(const s8*)(eal + off);
        } else if (q == 2) {
            ushort_t hh, ll;
            split_f16(s_d2[t * 16 + lo], hh, ll);
            aEAh[t][0] = (short)hh; aEAl[t][0] = (short)ll;
        }
    }

    // ---- GEMM1 (double-buffered B-frags): y1 = silu(hR@W1a + hC@W1b + [ea|d2]@G + b1')
    //      h-terms hi-only; ea/d2 keep lo correction ----
    {
        s8 nGh = *(const s8*)(wgh + (size_t)lane * 8);
        s8 nGl = *(const s8*)(wgl + (size_t)lane * 8);
        s8 nbh[4], nch[4];
#pragma unroll
        for (int kt = 0; kt < 4; ++kt) {
            size_t base = ((size_t)kt * 64 + lane) * 8;
            nbh[kt] = *(const s8*)(wAh + base);
            nch[kt] = *(const s8*)(wBh + base);
        }
#pragma unroll
        for (int nt = 0; nt < 8; ++nt) {
            s8 cGh = nGh, cGl = nGl;
            s8 cbh[4], cch[4];
#pragma unroll
            for (int kt = 0; kt < 4; ++kt) { cbh[kt] = nbh[kt]; cch[kt] = nch[kt]; }
            if (nt < 7) {
                nGh = *(const s8*)(wgh + ((size_t)(nt + 1) * 64 + lane) * 8);
                nGl = *(const s8*)(wgl + ((size_t)(nt + 1) * 64 + lane) * 8);
#pragma unroll
                for (int kt = 0; kt < 4; ++kt) {
                    size_t base = ((size_t)((nt + 1) * 4 + kt) * 64 + lane) * 8;
                    nbh[kt] = *(const s8*)(wAh + base);
                    nch[kt] = *(const s8*)(wBh + base);
                }
            }
            f4 aH[2], aL0[2];
#pragma unroll
            for (int t = 0; t < 2; ++t) {
                aH[t] = (f4){0.f,0.f,0.f,0.f};
                aL0[t] = (f4){0.f,0.f,0.f,0.f};
            }
#pragma unroll
            for (int t = 0; t < 2; ++t) {
                aH[t]  = mfma16(aEAh[t], cGh, aH[t]);
                aL0[t] = mfma16(aEAh[t], cGl, aL0[t]);
                aL0[t] = mfma16(aEAl[t], cGh, aL0[t]);
            }
#pragma unroll
            for (int kt = 0; kt < 4; ++kt) {
#pragma unroll
                for (int t = 0; t < 2; ++t) {
                    aH[t] = mfma16(aRh[t][kt], cbh[kt], aH[t]);
                    aH[t] = mfma16(aCh[t][kt], cch[kt], aH[t]);
                }
            }
            float bb = b1v[nt * 16 + lo];
#pragma unroll
            for (int t = 0; t < 2; ++t)
#pragma unroll
                for (int r = 0; r < 4; ++r) {
                    float v = silu_f(aH[t][r] + aL0[t][r] * INV4096 + bb);
                    int off = (t * 16 + q * 4 + r) * SACT + nt * 16 + lo;
                    s_acth[off] = f2h(v);
                }
        }
    }
    __syncthreads();   // B2

    // ---- GEMM2 (hi-only, double-buffered): m = silu(y1 @ W2 + b2), fused reduce ----
    s8 aYh[2][4];
#pragma unroll
    for (int t = 0; t < 2; ++t)
#pragma unroll
        for (int kt = 0; kt < 4; ++kt) {
            int off = (t * 16 + lo) * SACT + kt * 32 + q * 8;
            aYh[t][kt] = *(const s8*)&s_acth[off];
        }
    __syncthreads();   // B3

    int rowm[2][4];
#pragma unroll
    for (int t = 0; t < 2; ++t)
#pragma unroll
        for (int r = 0; r < 4; ++r) rowm[t][r] = s_row[t * 16 + q * 4 + r];
    const int dcnt = s_dcnt[0];

    {
        s8 nbh[4];
#pragma unroll
        for (int kt = 0; kt < 4; ++kt)
            nbh[kt] = *(const s8*)(wW2h + ((size_t)kt * 64 + lane) * 8);
#pragma unroll
        for (int nt = 0; nt < 8; ++nt) {
            s8 cbh[4];
#pragma unroll
            for (int kt = 0; kt < 4; ++kt) cbh[kt] = nbh[kt];
            if (nt < 7) {
#pragma unroll
                for (int kt = 0; kt < 4; ++kt)
                    nbh[kt] = *(const s8*)(wW2h + ((size_t)((nt + 1) * 4 + kt) * 64 + lane) * 8);
            }
            f4 aH[2];
#pragma unroll
            for (int t = 0; t < 2; ++t) aH[t] = (f4){0.f,0.f,0.f,0.f};
#pragma unroll
            for (int kt = 0; kt < 4; ++kt)
#pragma unroll
                for (int t = 0; t < 2; ++t)
                    aH[t] = mfma16(aYh[t][kt], cbh[kt], aH[t]);
            float bb = b2v[nt * 16 + lo];
#pragma unroll
            for (int t = 0; t < 2; ++t) {
#pragma unroll
                for (int r = 0; r < 4; ++r) {
                    aH[t][r] = silu_f(aH[t][r] + bb);
                    int off = (t * 16 + q * 4 + r) * SACT + nt * 16 + lo;
                    s_acth[off] = f2h(aH[t][r]);
                }
            }
            for (int di = 0; di < dcnt; ++di) {
                int dr = s_drows[di];
                float v = 0.f;
#pragma unroll
                for (int t = 0; t < 2; ++t)
#pragma unroll
                    for (int r = 0; r < 4; ++r) v += (rowm[t][r] == dr) ? aH[t][r] : 0.f;
                v += __shfl_xor(v, 16, 64);
                v += __shfl_xor(v, 32, 64);
                if (lane < 16) atomicAdd(&agg_h[(size_t)dr * HDIM + nt * 16 + lane], v);
            }
        }
    }
    __syncthreads();   // B4

    // ---- GEMM3 (hi-only, double-buffered): c = silu(m @ C1 + cb) ; w = tanh(c . c2) ----
    s8 aMh[2][4];
#pragma unroll
    for (int t = 0; t < 2; ++t)
#pragma unroll
        for (int kt = 0; kt < 4; ++kt) {
            int off = (t * 16 + lo) * SACT + kt * 32 + q * 8;
            aMh[t][kt] = *(const s8*)&s_acth[off];
        }

    float wpart[2][4] = {{0.f,0.f,0.f,0.f},{0.f,0.f,0.f,0.f}};
    {
        s8 nbh[4];
#pragma unroll
        for (int kt = 0; kt < 4; ++kt)
            nbh[kt] = *(const s8*)(wC1h + ((size_t)kt * 64 + lane) * 8);
#pragma unroll
        for (int nt = 0; nt < 8; ++nt) {
            s8 cbh[4];
#pragma unroll
            for (int kt = 0; kt < 4; ++kt) cbh[kt] = nbh[kt];
            if (nt < 7) {
#pragma unroll
                for (int kt = 0; kt < 4; ++kt)
                    nbh[kt] = *(const s8*)(wC1h + ((size_t)((nt + 1) * 4 + kt) * 64 + lane) * 8);
            }
            f4 aH[2];
#pragma unroll
            for (int t = 0; t < 2; ++t) aH[t] = (f4){0.f,0.f,0.f,0.f};
#pragma unroll
            for (int kt = 0; kt < 4; ++kt)
#pragma unroll
                for (int t = 0; t < 2; ++t)
                    aH[t] = mfma16(aMh[t][kt], cbh[kt], aH[t]);
            float bb = cbv[nt * 16 + lo];
            float cc = c2v[nt * 16 + lo];
#pragma unroll
            for (int t = 0; t < 2; ++t)
#pragma unroll
                for (int r = 0; r < 4; ++r)
                    wpart[t][r] += silu_f(aH[t][r] + bb) * cc;
        }
    }
#pragma unroll
    for (int t = 0; t < 2; ++t)
#pragma unroll
        for (int r = 0; r < 4; ++r) {
#pragma unroll
            for (int mask = 1; mask < 16; mask <<= 1)
                wpart[t][r] += __shfl_xor(wpart[t][r], mask, 16);
        }
    // trans vector + segmented reduce -> agg_x atomics per distinct row
    {
        float val[2][4];
#pragma unroll
        for (int t = 0; t < 2; ++t)
#pragma unroll
            for (int r = 0; r < 4; ++r) {
                int mm = t * 16 + q * 4 + r;
                val[t][r] = (lo < 3)
                    ? s_diff[mm][lo] * __builtin_amdgcn_rcpf(s_dist[mm] + EPSV) * tanh_fast(wpart[t][r])
                    : 0.f;
            }
        for (int di = 0; di < dcnt; ++di) {
            int dr = s_drows[di];
            float v = 0.f;
#pragma unroll
            for (int t = 0; t < 2; ++t)
#pragma unroll
                for (int r = 0; r < 4; ++r) v += (rowm[t][r] == dr) ? val[t][r] : 0.f;
            v += __shfl_xor(v, 16, 64);
            v += __shfl_xor(v, 32, 64);
            if (lane < 3) atomicAdd(&agg_x[dr * 3 + lane], v);
        }
    }
}

// ============ node kernel: 8 nodes/block; zeroes agg buffers; final layer writes output ============
__global__ __launch_bounds__(128) void node_kernel(
    float* __restrict__ h_feat, float* __restrict__ x_cur,
    ushort_t* __restrict__ hbf_hi,
    float* __restrict__ agg_h, float* __restrict__ agg_x,
    const float* __restrict__ mask,
    const float* __restrict__ n1p, const float* __restrict__ nb1p,
    const float* __restrict__ n2p, const float* __restrict__ nb2p, int layer,
    const float* __restrict__ x_in, float* __restrict__ out) {
    __shared__ float s_cat[8][2 * HDIM];
    __shared__ float s_u[8][HDIM];
    int nb = blockIdx.x * 8, j = threadIdx.x;
    const size_t w1o = (size_t)layer * 2 * HDIM * HDIM;
    const size_t w2o = (size_t)layer * HDIM * HDIM;
    const size_t bo  = (size_t)layer * HDIM;

#pragma unroll
    for (int e = 0; e < 8; ++e) {
        s_cat[e][j] = h_feat[(size_t)(nb + e) * HDIM + j];
        s_cat[e][HDIM + j] = agg_h[(size_t)(nb + e) * HDIM + j];
        agg_h[(size_t)(nb + e) * HDIM + j] = 0.f;   // re-zero for next layer
    }
    __syncthreads();

    float u[8];
    float b1 = nb1p[bo + j];
#pragma unroll
    for (int e = 0; e < 8; ++e) u[e] = b1;
    for (int i0 = 0; i0 < 2 * HDIM; i0 += 2) {
        float w0 = n1p[w1o + (size_t)i0 * HDIM + j];
        float w1 = n1p[w1o + (size_t)(i0 + 1) * HDIM + j];
#pragma unroll
        for (int e = 0; e < 8; ++e)
            u[e] += s_cat[e][i0] * w0 + s_cat[e][i0 + 1] * w1;
    }
#pragma unroll
    for (int e = 0; e < 8; ++e) s_u[e][j] = silu_f(u[e]);
    __syncthreads();

    float acc[8];
    float b2 = nb2p[bo + j];
#pragma unroll
    for (int e = 0; e < 8; ++e) acc[e] = b2;
    for (int i0 = 0; i0 < HDIM; i0 += 2) {
        float w0 = n2p[w2o + (size_t)i0 * HDIM + j];
        float w1 = n2p[w2o + (size_t)(i0 + 1) * HDIM + j];
#pragma unroll
        for (int e = 0; e < 8; ++e)
            acc[e] += s_u[e][i0] * w0 + s_u[e][i0 + 1] * w1;
    }
#pragma unroll
    for (int e = 0; e < 8; ++e) {
        float nh = s_cat[e][j] + acc[e];
        h_feat[(size_t)(nb + e) * HDIM + j] = nh;
        hbf_hi[(size_t)(nb + e) * HDIM + j] = f2h(nh);
    }
    if (j < 24) {
        int e = j / 3, c = j - e * 3;
        int idx = (nb + e) * 3 + c;
        float ax = agg_x[idx];
        agg_x[idx] = 0.f;   // re-zero for next layer
        float mv = mask[nb + e];
        float xn = x_cur[idx] + ax * mv;
        x_cur[idx] = xn;
        if (out) out[idx] = (xn - x_in[idx]) * mv;   // final layer: fused output write
    }
}

extern "C" void kernel_launch(void* const* d_in, const int* in_sizes, int n_in,
                              void* d_out, int out_size, void* d_ws, size_t ws_size,
                              hipStream_t stream) {
    const float* h    = (const float*)d_in[0];
    const float* x    = (const float*)d_in[1];
    const int*   ei   = (const int*)d_in[2];
    const float* ea   = (const float*)d_in[3];
    const float* t    = (const float*)d_in[4];
    const float* mask = (const float*)d_in[5];
    const float* tw1  = (const float*)d_in[6];
    const float* tb1  = (const float*)d_in[7];
    const float* tw2  = (const float*)d_in[8];
    const float* tb2  = (const float*)d_in[9];
    const float* new_ = (const float*)d_in[10];
    const float* neb  = (const float*)d_in[11];
    const float* eew  = (const float*)d_in[12];
    const float* eeb  = (const float*)d_in[13];
    const float* ew1  = (const float*)d_in[14];
    const float* eb1  = (const float*)d_in[15];
    const float* ew2  = (const float*)d_in[16];
    const float* eb2  = (const float*)d_in[17];
    const float* cw1  = (const float*)d_in[18];
    const float* cb1  = (const float*)d_in[19];
    const float* cw2  = (const float*)d_in[20];
    const float* nw1  = (const float*)d_in[21];
    const float* nb1  = (const float*)d_in[22];
    const float* nw2  = (const float*)d_in[23];
    const float* nb2  = (const float*)d_in[24];

    // ---- workspace carve-out (256 B aligned) ----
    char* p = (char*)d_ws;
    auto alloc = [&](size_t bytes) -> char* {
        char* r = p;
        p += (bytes + 255) & ~(size_t)255;
        return r;
    };
    float* t_emb    = (float*)alloc(HDIM * 4);
    float* h_feat   = (float*)alloc((size_t)N_NODES * HDIM * 4);
    float* x_cur    = (float*)alloc((size_t)N_NODES * 3 * 4);
    float* agg_h    = (float*)alloc((size_t)N_NODES * HDIM * 4);
    float* agg_x    = (float*)alloc((size_t)N_NODES * 3 * 4);
    float* bias1c   = (float*)alloc(NLAYERS * HDIM * 4);
    ushort_t* hbf_hi = (ushort_t*)alloc((size_t)N_NODES * HDIM * 2);
    ushort_t* wf_hi  = (ushort_t*)alloc((size_t)NLAYERS * 4 * 16384 * 2);
    ushort_t* g_hi   = (ushort_t*)alloc((size_t)NLAYERS * 4096 * 2);
    ushort_t* g_lo   = (ushort_t*)alloc((size_t)NLAYERS * 4096 * 2);
    int* deg        = (int*)alloc((size_t)N_NODES * 4);
    int* row_start  = (int*)alloc((size_t)(N_NODES + 1) * 4);
    int* cursor     = (int*)alloc((size_t)N_NODES * 4);
    int* csr_eid    = (int*)alloc((size_t)N_EDGES * 4);
    int* rows_s     = (int*)alloc((size_t)N_EDGES * 4);
    int* cols_s     = (int*)alloc((size_t)N_EDGES * 4);
    ushort_t* eah   = (ushort_t*)alloc((size_t)N_EDGES * EDGE_IN * 2);
    ushort_t* eal   = (ushort_t*)alloc((size_t)N_EDGES * EDGE_IN * 2);

    // single zero-init spans agg_h..agg_x (adjacent); node_kernel re-zeroes each layer
    size_t agg_span = (size_t)((char*)(agg_x + (size_t)N_NODES * 3) - (char*)agg_h);

    repack_weights<<<(NLAYERS * 4 * 16384 + 255) / 256, 256, 0, stream>>>(ew1, ew2, cw1, wf_hi);
    prep_g<<<(NLAYERS * 4096 + NLAYERS * 128 + 255) / 256, 256, 0, stream>>>(eew, eeb, ew1, eb1, g_hi, g_lo, bias1c);
    temb_kernel<<<1, HDIM, 0, stream>>>(t, tw1, tb1, tw2, tb2, t_emb);
    hfeat_kernel<<<(N_NODES + 7) / 8, 128, 0, stream>>>(h, new_, neb, t_emb, h_feat, hbf_hi);
    xinit_kernel<<<(N_NODES * 3 + 255) / 256, 256, 0, stream>>>(x, x_cur);
    hipMemsetAsync(agg_h, 0, agg_span, stream);

    hipMemsetAsync(deg, 0, (size_t)N_NODES * 4, stream);
    deg_kernel<<<(N_EDGES + 255) / 256, 256, 0, stream>>>(ei, deg);
    scan_kernel<<<1, 256, 0, stream>>>(deg, row_start, cursor);
    scatter_kernel<<<(N_EDGES + 255) / 256, 256, 0, stream>>>(ei, cursor, csr_eid);
    prep_edges<<<(N_EDGES + 255) / 256, 256, 0, stream>>>(ei, csr_eid, ea, rows_s, cols_s, eah, eal);

    for (int l = 0; l < NLAYERS; ++l) {
        edge_mfma_kernel<<<N_EDGES / 32, 64, 0, stream>>>(
            rows_s, cols_s, eah, eal, x_cur, hbf_hi, wf_hi, g_hi, g_lo, bias1c,
            eb2, cb1, cw2, l, agg_h, agg_x);
        node_kernel<<<N_NODES / 8, 128, 0, stream>>>(
            h_feat, x_cur, hbf_hi, agg_h, agg_x, mask, nw1, nb1, nw2, nb2, l,
            x, (l == NLAYERS - 1) ? (float*)d_out : nullptr);
    }
}

// Round 22
// 825.613 us; speedup vs baseline: 1.1022x; 1.1022x over previous
//
#include <hip/hip_runtime.h>
#include <hip/hip_bf16.h>

#define N_NODES 10000
#define N_EDGES 320000
#define HDIM 128
#define NODE_IN 64
#define EDGE_IN 16
#define NLAYERS 4
#define EPSV 1e-8f
#define SACT 136       // LDS activation row stride (elems)
#define INV4096 2.44140625e-4f

typedef unsigned short ushort_t;
typedef __attribute__((ext_vector_type(8))) short s8;        // 8 fp16 bit-pattern (4 VGPRs)
typedef __attribute__((ext_vector_type(8))) _Float16 h8;
typedef __attribute__((ext_vector_type(4))) float f4;

// silu via v_rcp_f32 (1 ulp) instead of IEEE divide (~10 instr)
__device__ __forceinline__ float silu_f(float z) {
    return z * __builtin_amdgcn_rcpf(1.0f + __expf(-z));
}
// tanh(x) = 1 - 2*rcp(exp(2x)+1); exact limits at +-inf
__device__ __forceinline__ float tanh_fast(float x) {
    float e = __expf(2.0f * x);
    return 1.0f - 2.0f * __builtin_amdgcn_rcpf(e + 1.0f);
}

__device__ __forceinline__ f4 mfma16(s8 a, s8 b, f4 c) {
    return __builtin_amdgcn_mfma_f32_16x16x32_f16(
        __builtin_bit_cast(h8, a), __builtin_bit_cast(h8, b), c, 0, 0, 0);
}

// fp32 -> fp16 hi + (residual*4096) lo   (rep error ~2^-23 relative)
__device__ __forceinline__ void split_f16(float x, ushort_t& hi, ushort_t& lo) {
    _Float16 h = (_Float16)x;
    float hf = (float)h;
    _Float16 l = (_Float16)((x - hf) * 4096.0f);
    hi = __builtin_bit_cast(ushort_t, h);
    lo = __builtin_bit_cast(ushort_t, l);
}
__device__ __forceinline__ ushort_t f2h(float x) {
    _Float16 h = (_Float16)x;
    return __builtin_bit_cast(ushort_t, h);
}

// ============ CSR build ============
__global__ void deg_kernel(const int* __restrict__ ei, int* __restrict__ deg) {
    int e = blockIdx.x * 256 + threadIdx.x;
    if (e < N_EDGES) atomicAdd(&deg[ei[e]], 1);
}

__global__ void scan_kernel(const int* __restrict__ deg, int* __restrict__ row_start,
                            int* __restrict__ cursor) {
    __shared__ int s_part[256];
    const int CH = 40;   // 256*40 = 10240 >= N_NODES
    int t = threadIdx.x;
    int base = t * CH;
    int sum = 0;
    for (int i = 0; i < CH; ++i) { int n = base + i; if (n < N_NODES) sum += deg[n]; }
    s_part[t] = sum;
    __syncthreads();
    for (int d = 1; d < 256; d <<= 1) {
        int v = (t >= d) ? s_part[t - d] : 0;
        __syncthreads();
        s_part[t] += v;
        __syncthreads();
    }
    int off = s_part[t] - sum;
    for (int i = 0; i < CH; ++i) {
        int n = base + i;
        if (n < N_NODES) { row_start[n] = off; cursor[n] = off; off += deg[n]; }
    }
    if (t == 255) row_start[N_NODES] = s_part[255];
}

__global__ void scatter_kernel(const int* __restrict__ ei, int* __restrict__ cursor,
                               int* __restrict__ csr_eid) {
    int e = blockIdx.x * 256 + threadIdx.x;
    if (e < N_EDGES) {
        int r = ei[e];
        int pos = atomicAdd(&cursor[r], 1);
        csr_eid[pos] = e;
    }
}

// ============ one-time slot-order prepack: rows/cols + ea split fp16 ============
__global__ void prep_edges(const int* __restrict__ ei, const int* __restrict__ csr_eid,
                           const float* __restrict__ ea,
                           int* __restrict__ rows_s, int* __restrict__ cols_s,
                           ushort_t* __restrict__ eah, ushort_t* __restrict__ eal) {
    int slot = blockIdx.x * 256 + threadIdx.x;
    if (slot >= N_EDGES) return;
    int eid = csr_eid[slot];
    rows_s[slot] = ei[eid];
    cols_s[slot] = ei[N_EDGES + eid];
    const float* src = ea + (size_t)eid * EDGE_IN;
#pragma unroll
    for (int i = 0; i < EDGE_IN; ++i) {
        ushort_t hh, ll;
        split_f16(src[i], hh, ll);
        eah[(size_t)slot * EDGE_IN + i] = hh;
        eal[(size_t)slot * EDGE_IN + i] = ll;
    }
}

// ============ prep 1: repack W1a,W1b,W2,C1 into MFMA B-frag order, fp16 hi only ============
__global__ void repack_weights(const float* __restrict__ ew1, const float* __restrict__ ew2,
                               const float* __restrict__ cw1,
                               ushort_t* __restrict__ wf_hi) {
    int gid = blockIdx.x * 256 + threadIdx.x;
    const int total = NLAYERS * 4 * 16384;
    if (gid >= total) return;
    int l   = gid / (4 * 16384);
    int rem = gid % (4 * 16384);
    int m4  = rem / 16384;
    int idx = rem & 16383;
    int b    = idx >> 9;
    int lane = (idx >> 3) & 63;
    int j    = idx & 7;
    int nt = b >> 2, kt = b & 3;
    int k = kt * 32 + ((lane >> 4) << 3) + j;
    int n = (nt << 4) + (lane & 15);
    float v;
    if (m4 == 0)      v = ew1[(size_t)l * 385 * 128 + (size_t)k * 128 + n];
    else if (m4 == 1) v = ew1[(size_t)l * 385 * 128 + (size_t)(128 + k) * 128 + n];
    else if (m4 == 2) v = ew2[(size_t)l * 16384 + k * 128 + n];
    else              v = cw1[(size_t)l * 16384 + k * 128 + n];
    wf_hi[gid] = f2h(v);
}

// ============ prep 2: G = eew @ W1c (K rows 0-15) + d2 weight row at k=16; frag-packed, split ============
__global__ void prep_g(const float* __restrict__ eew, const float* __restrict__ eeb,
                       const float* __restrict__ ew1, const float* __restrict__ eb1,
                       ushort_t* __restrict__ g_hi, ushort_t* __restrict__ g_lo,
                       float* __restrict__ bias1c) {
    int gid = blockIdx.x * 256 + threadIdx.x;
    const int T1 = NLAYERS * 4096;
    if (gid < T1) {
        int l = gid >> 12;
        int idx = gid & 4095;
        int nt = idx >> 9;
        int lane = (idx >> 3) & 63;
        int j = idx & 7;
        int q = lane >> 4;
        int n = (nt << 4) + (lane & 15);
        int k = q * 8 + j;
        float v = 0.f;
        if (k < EDGE_IN) {
            const float* w1c = ew1 + (size_t)l * 385 * 128 + (size_t)257 * 128;
            float acc = 0.f;
            for (int c = 0; c < HDIM; ++c) acc += eew[k * 128 + c] * w1c[(size_t)c * 128 + n];
            v = acc;
        } else if (k == EDGE_IN) {
            v = ew1[(size_t)l * 385 * 128 + (size_t)256 * 128 + n];   // d2 weight row
        }
        split_f16(v, g_hi[gid], g_lo[gid]);
    } else if (gid < T1 + NLAYERS * 128) {
        int r = gid - T1;
        int l = r >> 7;
        int n = r & 127;
        const float* w1c = ew1 + (size_t)l * 385 * 128 + (size_t)257 * 128;
        float acc = eb1[l * 128 + n];
        for (int c = 0; c < HDIM; ++c) acc += eeb[c] * w1c[(size_t)c * 128 + n];
        bias1c[r] = acc;
    }
}

// ============ t_emb ============
__global__ void temb_kernel(const float* t, const float* tw1, const float* tb1,
                            const float* tw2, const float* tb2, float* t_emb) {
    __shared__ float s_a[HDIM];
    int j = threadIdx.x;
    s_a[j] = silu_f(t[0] * tw1[j] + tb1[j]);
    __syncthreads();
    float acc = tb2[j];
    for (int k = 0; k < HDIM; ++k) acc += s_a[k] * tw2[k * HDIM + j];
    t_emb[j] = acc;
}

// ============ h_feat init: 8 nodes/block, weights amortized ============
__global__ __launch_bounds__(128) void hfeat_kernel(
    const float* __restrict__ h, const float* __restrict__ new_,
    const float* __restrict__ neb, const float* __restrict__ t_emb,
    float* __restrict__ h_feat, ushort_t* __restrict__ hbf_hi) {
    __shared__ float s_h[8][NODE_IN];
    int nb = blockIdx.x * 8, j = threadIdx.x;
#pragma unroll
    for (int it = 0; it < 4; ++it) {
        int idx = it * 128 + j;
        int e = idx >> 6, i = idx & 63;
        s_h[e][i] = h[(size_t)(nb + e) * NODE_IN + i];
    }
    __syncthreads();
    float base = neb[j] + t_emb[j];
    float acc[8];
#pragma unroll
    for (int e = 0; e < 8; ++e) acc[e] = base;
    for (int i = 0; i < NODE_IN; i += 2) {
        float w0 = new_[i * HDIM + j];
        float w1 = new_[(i + 1) * HDIM + j];
#pragma unroll
        for (int e = 0; e < 8; ++e)
            acc[e] += s_h[e][i] * w0 + s_h[e][i + 1] * w1;
    }
#pragma unroll
    for (int e = 0; e < 8; ++e) {
        h_feat[(size_t)(nb + e) * HDIM + j] = acc[e];
        hbf_hi[(size_t)(nb + e) * HDIM + j] = f2h(acc[e]);
    }
}

__global__ void xinit_kernel(const float* x, float* x_cur) {
    int idx = blockIdx.x * blockDim.x + threadIdx.x;
    if (idx < N_NODES * 3) x_cur[idx] = x[idx];
}

// ============ MFMA edge kernel: 1 block = 1 wave = 32 CSR slots (2 M-tiles) ============
// GEMM1: h-terms fp16-hi, ea/d2 keep lo correction (via G). GEMM2/GEMM3 hi-only.
// B-frags double-buffered across nt.
// (64,2): the ONLY spill-free point (verified: (64,3) and (64,4) both spill even at
// the slimmed ~128-reg footprint due to arch/AGPR split quantization).
__global__ __launch_bounds__(64, 2) void edge_mfma_kernel(
    const int* __restrict__ rows_s, const int* __restrict__ cols_s,
    const ushort_t* __restrict__ eah, const ushort_t* __restrict__ eal,
    const float* __restrict__ x_cur,
    const ushort_t* __restrict__ hbf_hi,
    const ushort_t* __restrict__ wf_hi,
    const ushort_t* __restrict__ g_hi, const ushort_t* __restrict__ g_lo,
    const float* __restrict__ bias1c,
    const float* __restrict__ eb2, const float* __restrict__ cb1, const float* __restrict__ cw2,
    int layer, float* __restrict__ agg_h, float* __restrict__ agg_x)
{
    __shared__ __align__(16) ushort_t s_acth[32 * SACT];
    __shared__ float s_d2[32], s_dist[32], s_diff[32][3];
    __shared__ int s_row[32], s_col[32];
    __shared__ int s_drows[32];
    __shared__ int s_dcnt[1];

    const int lane = threadIdx.x;
    const int lo = lane & 15, q = lane >> 4;
    const int e0 = blockIdx.x * 32;

    const ushort_t* wAh  = wf_hi + (size_t)layer * 4 * 16384;
    const ushort_t* wBh  = wAh + 16384;
    const ushort_t* wW2h = wAh + 32768;
    const ushort_t* wC1h = wAh + 49152;
    const ushort_t* wgh  = g_hi + (size_t)layer * 4096;
    const ushort_t* wgl  = g_lo + (size_t)layer * 4096;
    const float* b1v = bias1c + layer * 128;
    const float* b2v = eb2 + layer * 128;
    const float* cbv = cb1 + layer * 128;
    const float* c2v = cw2 + layer * 128;

    // ---- phase 0: geometry for 32 slots (coalesced slot-order reads) ----
    if (lane < 32) {
        int slot = e0 + lane;
        int r = rows_s[slot], c = cols_s[slot];
        s_row[lane] = r; s_col[lane] = c;
        float dx = x_cur[r * 3 + 0] - x_cur[c * 3 + 0];
        float dy = x_cur[r * 3 + 1] - x_cur[c * 3 + 1];
        float dz = x_cur[r * 3 + 2] - x_cur[c * 3 + 2];
        float d2 = dx * dx + dy * dy + dz * dz;
        s_d2[lane] = d2;
        s_dist[lane] = sqrtf(d2 + EPSV);
        s_diff[lane][0] = dx; s_diff[lane][1] = dy; s_diff[lane][2] = dz;
    }
    __syncthreads();   // B1 (single-wave: cheap)

    // distinct-row list via ballot (CSR slots row-sorted)
    {
        bool head = false;
        if (lane < 32) {
            int r = s_row[lane];
            int prev = (lane == 0) ? -1 : s_row[lane - 1];
            head = (r != prev);
        }
        unsigned long long b = __ballot(head);
        if (head) {
            int idx = __popcll(b & ((1ull << lane) - 1ull));
            s_drows[idx] = s_row[lane];
        }
        if (lane == 0) s_dcnt[0] = __popcll(b);
    }

    // ---- A fragments for both tiles (hi only) ----
    int erT[2], ecT[2];
#pragma unroll
    for (int t = 0; t < 2; ++t) { erT[t] = s_row[t * 16 + lo]; ecT[t] = s_col[t * 16 + lo]; }

    s8 aRh[2][4], aCh[2][4];
#pragma unroll
    for (int t = 0; t < 2; ++t)
#pragma unroll
        for (int kt = 0; kt < 4; ++kt) {
            aRh[t][kt] = *(const s8*)(hbf_hi + (size_t)erT[t] * 128 + kt * 32 + q * 8);
            aCh[t][kt] = *(const s8*)(hbf_hi + (size_t)ecT[t] * 128 + kt * 32 + q * 8);
        }
    // ea (k=0..15, prepacked fp16 split, coalesced) + d2 (k=16, lanes q==2 slot j=0)
    s8 aEAh[2], aEAl[2];
#pragma unroll
    for (int t = 0; t < 2; ++t) {
        aEAh[t] = (s8){0,0,0,0,0,0,0,0};
        aEAl[t] = (s8){0,0,0,0,0,0,0,0};
        if (q < 2) {
            size_t off = (size_t)(e0 + t * 16 + lo) * EDGE_IN + q * 8;
            aEAh[t] = *(const s8*)(eah + off);
            aEAl[t] = *(const s8*)(eal + off);
        } else if (q == 2) {
            ushort_t hh, ll;
            split_f16(s_d2[t * 16 + lo], hh, ll);
            aEAh[t][0] = (short)hh; aEAl[t][0] = (short)ll;
        }
    }

    // ---- GEMM1 (double-buffered B-frags): y1 = silu(hR@W1a + hC@W1b + [ea|d2]@G + b1')
    //      h-terms hi-only; ea/d2 keep lo correction ----
    {
        s8 nGh = *(const s8*)(wgh + (size_t)lane * 8);
        s8 nGl = *(const s8*)(wgl + (size_t)lane * 8);
        s8 nbh[4], nch[4];
#pragma unroll
        for (int kt = 0; kt < 4; ++kt) {
            size_t base = ((size_t)kt * 64 + lane) * 8;
            nbh[kt] = *(const s8*)(wAh + base);
            nch[kt] = *(const s8*)(wBh + base);
        }
#pragma unroll
        for (int nt = 0; nt < 8; ++nt) {
            s8 cGh = nGh, cGl = nGl;
            s8 cbh[4], cch[4];
#pragma unroll
            for (int kt = 0; kt < 4; ++kt) { cbh[kt] = nbh[kt]; cch[kt] = nch[kt]; }
            if (nt < 7) {
                nGh = *(const s8*)(wgh + ((size_t)(nt + 1) * 64 + lane) * 8);
                nGl = *(const s8*)(wgl + ((size_t)(nt + 1) * 64 + lane) * 8);
#pragma unroll
                for (int kt = 0; kt < 4; ++kt) {
                    size_t base = ((size_t)((nt + 1) * 4 + kt) * 64 + lane) * 8;
                    nbh[kt] = *(const s8*)(wAh + base);
                    nch[kt] = *(const s8*)(wBh + base);
                }
            }
            f4 aH[2], aL0[2];
#pragma unroll
            for (int t = 0; t < 2; ++t) {
                aH[t] = (f4){0.f,0.f,0.f,0.f};
                aL0[t] = (f4){0.f,0.f,0.f,0.f};
            }
#pragma unroll
            for (int t = 0; t < 2; ++t) {
                aH[t]  = mfma16(aEAh[t], cGh, aH[t]);
                aL0[t] = mfma16(aEAh[t], cGl, aL0[t]);
                aL0[t] = mfma16(aEAl[t], cGh, aL0[t]);
            }
#pragma unroll
            for (int kt = 0; kt < 4; ++kt) {
#pragma unroll
                for (int t = 0; t < 2; ++t) {
                    aH[t] = mfma16(aRh[t][kt], cbh[kt], aH[t]);
                    aH[t] = mfma16(aCh[t][kt], cch[kt], aH[t]);
                }
            }
            float bb = b1v[nt * 16 + lo];
#pragma unroll
            for (int t = 0; t < 2; ++t)
#pragma unroll
                for (int r = 0; r < 4; ++r) {
                    float v = silu_f(aH[t][r] + aL0[t][r] * INV4096 + bb);
                    int off = (t * 16 + q * 4 + r) * SACT + nt * 16 + lo;
                    s_acth[off] = f2h(v);
                }
        }
    }
    __syncthreads();   // B2

    // ---- GEMM2 (hi-only, double-buffered): m = silu(y1 @ W2 + b2), fused reduce ----
    s8 aYh[2][4];
#pragma unroll
    for (int t = 0; t < 2; ++t)
#pragma unroll
        for (int kt = 0; kt < 4; ++kt) {
            int off = (t * 16 + lo) * SACT + kt * 32 + q * 8;
            aYh[t][kt] = *(const s8*)&s_acth[off];
        }
    __syncthreads();   // B3

    int rowm[2][4];
#pragma unroll
    for (int t = 0; t < 2; ++t)
#pragma unroll
        for (int r = 0; r < 4; ++r) rowm[t][r] = s_row[t * 16 + q * 4 + r];
    const int dcnt = s_dcnt[0];

    {
        s8 nbh[4];
#pragma unroll
        for (int kt = 0; kt < 4; ++kt)
            nbh[kt] = *(const s8*)(wW2h + ((size_t)kt * 64 + lane) * 8);
#pragma unroll
        for (int nt = 0; nt < 8; ++nt) {
            s8 cbh[4];
#pragma unroll
            for (int kt = 0; kt < 4; ++kt) cbh[kt] = nbh[kt];
            if (nt < 7) {
#pragma unroll
                for (int kt = 0; kt < 4; ++kt)
                    nbh[kt] = *(const s8*)(wW2h + ((size_t)((nt + 1) * 4 + kt) * 64 + lane) * 8);
            }
            f4 aH[2];
#pragma unroll
            for (int t = 0; t < 2; ++t) aH[t] = (f4){0.f,0.f,0.f,0.f};
#pragma unroll
            for (int kt = 0; kt < 4; ++kt)
#pragma unroll
                for (int t = 0; t < 2; ++t)
                    aH[t] = mfma16(aYh[t][kt], cbh[kt], aH[t]);
            float bb = b2v[nt * 16 + lo];
#pragma unroll
            for (int t = 0; t < 2; ++t) {
#pragma unroll
                for (int r = 0; r < 4; ++r) {
                    aH[t][r] = silu_f(aH[t][r] + bb);
                    int off = (t * 16 + q * 4 + r) * SACT + nt * 16 + lo;
                    s_acth[off] = f2h(aH[t][r]);
                }
            }
            for (int di = 0; di < dcnt; ++di) {
                int dr = s_drows[di];
                float v = 0.f;
#pragma unroll
                for (int t = 0; t < 2; ++t)
#pragma unroll
                    for (int r = 0; r < 4; ++r) v += (rowm[t][r] == dr) ? aH[t][r] : 0.f;
                v += __shfl_xor(v, 16, 64);
                v += __shfl_xor(v, 32, 64);
                if (lane < 16) atomicAdd(&agg_h[(size_t)dr * HDIM + nt * 16 + lane], v);
            }
        }
    }
    __syncthreads();   // B4

    // ---- GEMM3 (hi-only, double-buffered): c = silu(m @ C1 + cb) ; w = tanh(c . c2) ----
    s8 aMh[2][4];
#pragma unroll
    for (int t = 0; t < 2; ++t)
#pragma unroll
        for (int kt = 0; kt < 4; ++kt) {
            int off = (t * 16 + lo) * SACT + kt * 32 + q * 8;
            aMh[t][kt] = *(const s8*)&s_acth[off];
        }

    float wpart[2][4] = {{0.f,0.f,0.f,0.f},{0.f,0.f,0.f,0.f}};
    {
        s8 nbh[4];
#pragma unroll
        for (int kt = 0; kt < 4; ++kt)
            nbh[kt] = *(const s8*)(wC1h + ((size_t)kt * 64 + lane) * 8);
#pragma unroll
        for (int nt = 0; nt < 8; ++nt) {
            s8 cbh[4];
#pragma unroll
            for (int kt = 0; kt < 4; ++kt) cbh[kt] = nbh[kt];
            if (nt < 7) {
#pragma unroll
                for (int kt = 0; kt < 4; ++kt)
                    nbh[kt] = *(const s8*)(wC1h + ((size_t)((nt + 1) * 4 + kt) * 64 + lane) * 8);
            }
            f4 aH[2];
#pragma unroll
            for (int t = 0; t < 2; ++t) aH[t] = (f4){0.f,0.f,0.f,0.f};
#pragma unroll
            for (int kt = 0; kt < 4; ++kt)
#pragma unroll
                for (int t = 0; t < 2; ++t)
                    aH[t] = mfma16(aMh[t][kt], cbh[kt], aH[t]);
            float bb = cbv[nt * 16 + lo];
            float cc = c2v[nt * 16 + lo];
#pragma unroll
            for (int t = 0; t < 2; ++t)
#pragma unroll
                for (int r = 0; r < 4; ++r)
                    wpart[t][r] += silu_f(aH[t][r] + bb) * cc;
        }
    }
#pragma unroll
    for (int t = 0; t < 2; ++t)
#pragma unroll
        for (int r = 0; r < 4; ++r) {
#pragma unroll
            for (int mask = 1; mask < 16; mask <<= 1)
                wpart[t][r] += __shfl_xor(wpart[t][r], mask, 16);
        }
    // trans vector + segmented reduce -> agg_x atomics per distinct row
    {
        float val[2][4];
#pragma unroll
        for (int t = 0; t < 2; ++t)
#pragma unroll
            for (int r = 0; r < 4; ++r) {
                int mm = t * 16 + q * 4 + r;
                val[t][r] = (lo < 3)
                    ? s_diff[mm][lo] * __builtin_amdgcn_rcpf(s_dist[mm] + EPSV) * tanh_fast(wpart[t][r])
                    : 0.f;
            }
        for (int di = 0; di < dcnt; ++di) {
            int dr = s_drows[di];
            float v = 0.f;
#pragma unroll
            for (int t = 0; t < 2; ++t)
#pragma unroll
                for (int r = 0; r < 4; ++r) v += (rowm[t][r] == dr) ? val[t][r] : 0.f;
            v += __shfl_xor(v, 16, 64);
            v += __shfl_xor(v, 32, 64);
            if (lane < 3) atomicAdd(&agg_x[dr * 3 + lane], v);
        }
    }
}

// ============ node kernel: 8 nodes/block; zeroes agg buffers; final layer writes output ============
__global__ __launch_bounds__(128) void node_kernel(
    float* __restrict__ h_feat, float* __restrict__ x_cur,
    ushort_t* __restrict__ hbf_hi,
    float* __restrict__ agg_h, float* __restrict__ agg_x,
    const float* __restrict__ mask,
    const float* __restrict__ n1p, const float* __restrict__ nb1p,
    const float* __restrict__ n2p, const float* __restrict__ nb2p, int layer,
    const float* __restrict__ x_in, float* __restrict__ out) {
    __shared__ float s_cat[8][2 * HDIM];
    __shared__ float s_u[8][HDIM];
    int nb = blockIdx.x * 8, j = threadIdx.x;
    const size_t w1o = (size_t)layer * 2 * HDIM * HDIM;
    const size_t w2o = (size_t)layer * HDIM * HDIM;
    const size_t bo  = (size_t)layer * HDIM;

#pragma unroll
    for (int e = 0; e < 8; ++e) {
        s_cat[e][j] = h_feat[(size_t)(nb + e) * HDIM + j];
        s_cat[e][HDIM + j] = agg_h[(size_t)(nb + e) * HDIM + j];
        agg_h[(size_t)(nb + e) * HDIM + j] = 0.f;   // re-zero for next layer
    }
    __syncthreads();

    float u[8];
    float b1 = nb1p[bo + j];
#pragma unroll
    for (int e = 0; e < 8; ++e) u[e] = b1;
    for (int i0 = 0; i0 < 2 * HDIM; i0 += 2) {
        float w0 = n1p[w1o + (size_t)i0 * HDIM + j];
        float w1 = n1p[w1o + (size_t)(i0 + 1) * HDIM + j];
#pragma unroll
        for (int e = 0; e < 8; ++e)
            u[e] += s_cat[e][i0] * w0 + s_cat[e][i0 + 1] * w1;
    }
#pragma unroll
    for (int e = 0; e < 8; ++e) s_u[e][j] = silu_f(u[e]);
    __syncthreads();

    float acc[8];
    float b2 = nb2p[bo + j];
#pragma unroll
    for (int e = 0; e < 8; ++e) acc[e] = b2;
    for (int i0 = 0; i0 < HDIM; i0 += 2) {
        float w0 = n2p[w2o + (size_t)i0 * HDIM + j];
        float w1 = n2p[w2o + (size_t)(i0 + 1) * HDIM + j];
#pragma unroll
        for (int e = 0; e < 8; ++e)
            acc[e] += s_u[e][i0] * w0 + s_u[e][i0 + 1] * w1;
    }
#pragma unroll
    for (int e = 0; e < 8; ++e) {
        float nh = s_cat[e][j] + acc[e];
        h_feat[(size_t)(nb + e) * HDIM + j] = nh;
        hbf_hi[(size_t)(nb + e) * HDIM + j] = f2h(nh);
    }
    if (j < 24) {
        int e = j / 3, c = j - e * 3;
        int idx = (nb + e) * 3 + c;
        float ax = agg_x[idx];
        agg_x[idx] = 0.f;   // re-zero for next layer
        float mv = mask[nb + e];
        float xn = x_cur[idx] + ax * mv;
        x_cur[idx] = xn;
        if (out) out[idx] = (xn - x_in[idx]) * mv;   // final layer: fused output write
    }
}

extern "C" void kernel_launch(void* const* d_in, const int* in_sizes, int n_in,
                              void* d_out, int out_size, void* d_ws, size_t ws_size,
                              hipStream_t stream) {
    const float* h    = (const float*)d_in[0];
    const float* x    = (const float*)d_in[1];
    const int*   ei   = (const int*)d_in[2];
    const float* ea   = (const float*)d_in[3];
    const float* t    = (const float*)d_in[4];
    const float* mask = (const float*)d_in[5];
    const float* tw1  = (const float*)d_in[6];
    const float* tb1  = (const float*)d_in[7];
    const float* tw2  = (const float*)d_in[8];
    const float* tb2  = (const float*)d_in[9];
    const float* new_ = (const float*)d_in[10];
    const float* neb  = (const float*)d_in[11];
    const float* eew  = (const float*)d_in[12];
    const float* eeb  = (const float*)d_in[13];
    const float* ew1  = (const float*)d_in[14];
    const float* eb1  = (const float*)d_in[15];
    const float* ew2  = (const float*)d_in[16];
    const float* eb2  = (const float*)d_in[17];
    const float* cw1  = (const float*)d_in[18];
    const float* cb1  = (const float*)d_in[19];
    const float* cw2  = (const float*)d_in[20];
    const float* nw1  = (const float*)d_in[21];
    const float* nb1  = (const float*)d_in[22];
    const float* nw2  = (const float*)d_in[23];
    const float* nb2  = (const float*)d_in[24];

    // ---- workspace carve-out (256 B aligned) ----
    char* p = (char*)d_ws;
    auto alloc = [&](size_t bytes) -> char* {
        char* r = p;
        p += (bytes + 255) & ~(size_t)255;
        return r;
    };
    float* t_emb    = (float*)alloc(HDIM * 4);
    float* h_feat   = (float*)alloc((size_t)N_NODES * HDIM * 4);
    float* x_cur    = (float*)alloc((size_t)N_NODES * 3 * 4);
    float* agg_h    = (float*)alloc((size_t)N_NODES * HDIM * 4);
    float* agg_x    = (float*)alloc((size_t)N_NODES * 3 * 4);
    float* bias1c   = (float*)alloc(NLAYERS * HDIM * 4);
    ushort_t* hbf_hi = (ushort_t*)alloc((size_t)N_NODES * HDIM * 2);
    ushort_t* wf_hi  = (ushort_t*)alloc((size_t)NLAYERS * 4 * 16384 * 2);
    ushort_t* g_hi   = (ushort_t*)alloc((size_t)NLAYERS * 4096 * 2);
    ushort_t* g_lo   = (ushort_t*)alloc((size_t)NLAYERS * 4096 * 2);
    int* deg        = (int*)alloc((size_t)N_NODES * 4);
    int* row_start  = (int*)alloc((size_t)(N_NODES + 1) * 4);
    int* cursor     = (int*)alloc((size_t)N_NODES * 4);
    int* csr_eid    = (int*)alloc((size_t)N_EDGES * 4);
    int* rows_s     = (int*)alloc((size_t)N_EDGES * 4);
    int* cols_s     = (int*)alloc((size_t)N_EDGES * 4);
    ushort_t* eah   = (ushort_t*)alloc((size_t)N_EDGES * EDGE_IN * 2);
    ushort_t* eal   = (ushort_t*)alloc((size_t)N_EDGES * EDGE_IN * 2);

    // single zero-init spans agg_h..agg_x (adjacent); node_kernel re-zeroes each layer
    size_t agg_span = (size_t)((char*)(agg_x + (size_t)N_NODES * 3) - (char*)agg_h);

    repack_weights<<<(NLAYERS * 4 * 16384 + 255) / 256, 256, 0, stream>>>(ew1, ew2, cw1, wf_hi);
    prep_g<<<(NLAYERS * 4096 + NLAYERS * 128 + 255) / 256, 256, 0, stream>>>(eew, eeb, ew1, eb1, g_hi, g_lo, bias1c);
    temb_kernel<<<1, HDIM, 0, stream>>>(t, tw1, tb1, tw2, tb2, t_emb);
    hfeat_kernel<<<(N_NODES + 7) / 8, 128, 0, stream>>>(h, new_, neb, t_emb, h_feat, hbf_hi);
    xinit_kernel<<<(N_NODES * 3 + 255) / 256, 256, 0, stream>>>(x, x_cur);
    hipMemsetAsync(agg_h, 0, agg_span, stream);

    hipMemsetAsync(deg, 0, (size_t)N_NODES * 4, stream);
    deg_kernel<<<(N_EDGES + 255) / 256, 256, 0, stream>>>(ei, deg);
    scan_kernel<<<1, 256, 0, stream>>>(deg, row_start, cursor);
    scatter_kernel<<<(N_EDGES + 255) / 256, 256, 0, stream>>>(ei, cursor, csr_eid);
    prep_edges<<<(N_EDGES + 255) / 256, 256, 0, stream>>>(ei, csr_eid, ea, rows_s, cols_s, eah, eal);

    for (int l = 0; l < NLAYERS; ++l) {
        edge_mfma_kernel<<<N_EDGES / 32, 64, 0, stream>>>(
            rows_s, cols_s, eah, eal, x_cur, hbf_hi, wf_hi, g_hi, g_lo, bias1c,
            eb2, cb1, cw2, l, agg_h, agg_x);
        node_kernel<<<N_NODES / 8, 128, 0, stream>>>(
            h_feat, x_cur, hbf_hi, agg_h, agg_x, mask, nw1, nb1, nw2, nb2, l,
            x, (l == NLAYERS - 1) ? (float*)d_out : nullptr);
    }
}